// Round 3
// baseline (283.525 us; speedup 1.0000x reference)
//
#include <hip/hip_runtime.h>
#include <hip/hip_bf16.h>

// ---------- types ----------
typedef __attribute__((ext_vector_type(8))) short s16x8;   // 8 bf16 (4 VGPR)
typedef __attribute__((ext_vector_type(4))) short s16x4;   // 4 bf16
typedef __attribute__((ext_vector_type(4))) float f32x4;

#define MFMA16(a, b, c) __builtin_amdgcn_mfma_f32_16x16x32_bf16(a, b, c, 0, 0, 0)

__device__ __forceinline__ short f2bf(float f) {
  unsigned int x = __builtin_bit_cast(unsigned int, f);
  x += 0x7fffu + ((x >> 16) & 1u);   // RNE; inputs always finite here
  return (short)(x >> 16);
}

// permuted LDS column so a lane's 8 fragment elements are contiguous:
// frag elem j (lane group g): j<4 -> k=4g+j ; j>=4 -> k=16+4g+(j-4)
__device__ __forceinline__ int cperm(int k) {
  return ((k & 12) << 1) | ((k >> 4) << 2) | (k & 3);
}

#define LDT 40   // padded LDS row length for GEMM tiles

// ---------- fp32 -> bf16 convert ----------
__global__ void cvt_f32_bf16(const float* __restrict__ in, short* __restrict__ out, int n) {
  int idx = blockIdx.x * blockDim.x + threadIdx.x;
  int stride = gridDim.x * blockDim.x;
  for (int i = idx * 4; i < n; i += stride * 4) {
    float4 v = *(const float4*)(in + i);
    s16x4 o;
    o[0] = f2bf(v.x); o[1] = f2bf(v.y); o[2] = f2bf(v.z); o[3] = f2bf(v.w);
    *(s16x4*)(out + i) = o;
  }
}

// ---------- GEMM1: qkv = Xb @ Wqkv + b, scatter to Q/K/V [B,N,S,H] bf16 ----------
// Q is pre-scaled by 1/sqrt(H)=0.125 so attention skips the per-element mul.
__global__ __launch_bounds__(256) void gemm_qkv(
    const short* __restrict__ X, const short* __restrict__ W,
    const float* __restrict__ bias,
    short* __restrict__ Qo, short* __restrict__ Ko, short* __restrict__ Vo) {
  const int N = 3072, Kd = 1024;
  __shared__ short As[128 * LDT];
  __shared__ short Bs[128 * LDT];
  int t = threadIdx.x;
  int nTN = N / 128;
  int m0 = (blockIdx.x / nTN) * 128;
  int n0 = (blockIdx.x % nTN) * 128;
  int lane = t & 63, w = t >> 6;
  int wr = (w >> 1) * 64, wc = (w & 1) * 64;
  int r = lane & 15, g = lane >> 4;

  int ar = t >> 1;
  int ak = (t & 1) << 4;
  int bk = t & 31;
  int bc = (t >> 5) << 4;
  int cbk = cperm(bk);

  f32x4 acc[4][4];
  const f32x4 z4 = {0.f, 0.f, 0.f, 0.f};
#pragma unroll
  for (int i = 0; i < 4; ++i)
#pragma unroll
    for (int j = 0; j < 4; ++j) acc[i][j] = z4;

  for (int kt = 0; kt < Kd; kt += 32) {
    if (kt) __syncthreads();
    const short* xr = X + (size_t)(m0 + ar) * Kd + kt + ak;
    s16x8 va0 = *(const s16x8*)(xr);
    s16x8 va1 = *(const s16x8*)(xr + 8);
    short* Ad = &As[ar * LDT];
    *(s16x4*)(Ad + cperm(ak))      = __builtin_shufflevector(va0, va0, 0, 1, 2, 3);
    *(s16x4*)(Ad + cperm(ak + 4))  = __builtin_shufflevector(va0, va0, 4, 5, 6, 7);
    *(s16x4*)(Ad + cperm(ak + 8))  = __builtin_shufflevector(va1, va1, 0, 1, 2, 3);
    *(s16x4*)(Ad + cperm(ak + 12)) = __builtin_shufflevector(va1, va1, 4, 5, 6, 7);
    const short* wrp = W + (size_t)(kt + bk) * N + n0 + bc;
    s16x8 vb0 = *(const s16x8*)(wrp);
    s16x8 vb1 = *(const s16x8*)(wrp + 8);
#pragma unroll
    for (int i = 0; i < 8; ++i) Bs[(bc + i) * LDT + cbk] = vb0[i];
#pragma unroll
    for (int i = 0; i < 8; ++i) Bs[(bc + 8 + i) * LDT + cbk] = vb1[i];
    __syncthreads();

    s16x8 af[4], bfr[4];
#pragma unroll
    for (int mi = 0; mi < 4; ++mi)
      af[mi] = *(const s16x8*)(&As[(wr + mi * 16 + r) * LDT + g * 8]);
#pragma unroll
    for (int ni = 0; ni < 4; ++ni)
      bfr[ni] = *(const s16x8*)(&Bs[(wc + ni * 16 + r) * LDT + g * 8]);
#pragma unroll
    for (int mi = 0; mi < 4; ++mi)
#pragma unroll
      for (int ni = 0; ni < 4; ++ni)
        acc[mi][ni] = MFMA16(af[mi], bfr[ni], acc[mi][ni]);
  }

#pragma unroll
  for (int ni = 0; ni < 4; ++ni) {
    int col = n0 + wc + ni * 16 + r;
    float bv = bias[col];
    int which = col >> 10;
    int rem = col & 1023;
    int head = rem >> 6, h = rem & 63;
    short* dst = (which == 0) ? Qo : (which == 1) ? Ko : Vo;
    float qsc = (which == 0) ? 0.125f : 1.0f;
#pragma unroll
    for (int mi = 0; mi < 4; ++mi)
#pragma unroll
      for (int e = 0; e < 4; ++e) {
        int row = m0 + wr + mi * 16 + g * 4 + e;
        int b = row >> 11, s = row & 2047;
        dst[((size_t)(b * 16 + head) * 2048 + s) * 64 + h] = f2bf((acc[mi][ni][e] + bv) * qsc);
      }
  }
}

// ---------- GEMM2: out = AttnOut @ Wout + b, fp32 out ----------
__global__ __launch_bounds__(256) void gemm_out(
    const short* __restrict__ X, const short* __restrict__ W,
    const float* __restrict__ bias, float* __restrict__ Out) {
  const int N = 1024, Kd = 1024;
  __shared__ short As[128 * LDT];
  __shared__ short Bs[128 * LDT];
  int t = threadIdx.x;
  int nTN = N / 128;
  int m0 = (blockIdx.x / nTN) * 128;
  int n0 = (blockIdx.x % nTN) * 128;
  int lane = t & 63, w = t >> 6;
  int wr = (w >> 1) * 64, wc = (w & 1) * 64;
  int r = lane & 15, g = lane >> 4;
  int ar = t >> 1, ak = (t & 1) << 4;
  int bk = t & 31, bc = (t >> 5) << 4;
  int cbk = cperm(bk);

  f32x4 acc[4][4];
  const f32x4 z4 = {0.f, 0.f, 0.f, 0.f};
#pragma unroll
  for (int i = 0; i < 4; ++i)
#pragma unroll
    for (int j = 0; j < 4; ++j) acc[i][j] = z4;

  for (int kt = 0; kt < Kd; kt += 32) {
    if (kt) __syncthreads();
    const short* xr = X + (size_t)(m0 + ar) * Kd + kt + ak;
    s16x8 va0 = *(const s16x8*)(xr);
    s16x8 va1 = *(const s16x8*)(xr + 8);
    short* Ad = &As[ar * LDT];
    *(s16x4*)(Ad + cperm(ak))      = __builtin_shufflevector(va0, va0, 0, 1, 2, 3);
    *(s16x4*)(Ad + cperm(ak + 4))  = __builtin_shufflevector(va0, va0, 4, 5, 6, 7);
    *(s16x4*)(Ad + cperm(ak + 8))  = __builtin_shufflevector(va1, va1, 0, 1, 2, 3);
    *(s16x4*)(Ad + cperm(ak + 12)) = __builtin_shufflevector(va1, va1, 4, 5, 6, 7);
    const short* wrp = W + (size_t)(kt + bk) * N + n0 + bc;
    s16x8 vb0 = *(const s16x8*)(wrp);
    s16x8 vb1 = *(const s16x8*)(wrp + 8);
#pragma unroll
    for (int i = 0; i < 8; ++i) Bs[(bc + i) * LDT + cbk] = vb0[i];
#pragma unroll
    for (int i = 0; i < 8; ++i) Bs[(bc + 8 + i) * LDT + cbk] = vb1[i];
    __syncthreads();

    s16x8 af[4], bfr[4];
#pragma unroll
    for (int mi = 0; mi < 4; ++mi)
      af[mi] = *(const s16x8*)(&As[(wr + mi * 16 + r) * LDT + g * 8]);
#pragma unroll
    for (int ni = 0; ni < 4; ++ni)
      bfr[ni] = *(const s16x8*)(&Bs[(wc + ni * 16 + r) * LDT + g * 8]);
#pragma unroll
    for (int mi = 0; mi < 4; ++mi)
#pragma unroll
      for (int ni = 0; ni < 4; ++ni)
        acc[mi][ni] = MFMA16(af[mi], bfr[ni], acc[mi][ni]);
  }

#pragma unroll
  for (int ni = 0; ni < 4; ++ni) {
    int col = n0 + wc + ni * 16 + r;
    float bv = bias[col];
#pragma unroll
    for (int mi = 0; mi < 4; ++mi)
#pragma unroll
      for (int e = 0; e < 4; ++e) {
        int row = m0 + wr + mi * 16 + g * 4 + e;
        Out[(size_t)row * N + col] = acc[mi][ni][e] + bv;
      }
  }
}

// ---------- causal flash attention ----------
// Pair-balanced: block handles q-tiles (15-pr) then (pr): every block = 34 kv-tiles.
// KV tile = 64; V register-prefetch + LDS; K register double-buffer (1 tile ahead).
// Swapped QK^T: st = mfma(K,Q) -> S^T; per-q stats at lane r = lane&15.
#define LDTV 72  // V LDS row stride (64 cols + pad)
__global__ __launch_bounds__(256) void attn(
    const short* __restrict__ Qb, const short* __restrict__ Kb,
    const short* __restrict__ Vb, short* __restrict__ Ob) {
  const int S = 2048, H = 64;
  int bid = blockIdx.x;
  int bn = bid & 63;
  int pr = bid >> 6;                 // pair index 0..7
  int batch = bn >> 4, head = bn & 15;
  int t = threadIdx.x, lane = t & 63, w = t >> 6;
  int r = lane & 15, g = lane >> 4;

  const short* Qh = Qb + (size_t)bn * S * H;
  const short* Kh = Kb + (size_t)bn * S * H;
  const short* Vh = Vb + (size_t)bn * S * H;

  __shared__ short Vs[64 * LDTV];

  int vr = lane;
  int hbase = w * 16;
  int vcol = ((vr >> 5) << 5) + cperm(vr & 31);
  const f32x4 z4 = {0.f, 0.f, 0.f, 0.f};

#pragma unroll
  for (int ph = 0; ph < 2; ++ph) {
    int qt = ph ? pr : (15 - pr);
    int q0 = qt * 128;
    int qw = q0 + w * 32;
    int ntiles = qt * 2 + 2;

    // Q fragments (B-operand [k=h][col=q]); Q already scaled by 1/8
    s16x8 qf[2][2];
#pragma unroll
    for (int n = 0; n < 2; ++n)
#pragma unroll
      for (int ks = 0; ks < 2; ++ks) {
        const short* qr = Qh + (size_t)(qw + n * 16 + r) * H + ks * 32 + g * 4;
        s16x4 lo = *(const s16x4*)(qr);
        s16x4 hi = *(const s16x4*)(qr + 16);
        qf[n][ks] = __builtin_shufflevector(lo, hi, 0, 1, 2, 3, 4, 5, 6, 7);
      }

    f32x4 o[2][4];
#pragma unroll
    for (int n = 0; n < 2; ++n)
#pragma unroll
      for (int hb = 0; hb < 4; ++hb) o[n][hb] = z4;
    float mrun[2] = {-__builtin_inff(), -__builtin_inff()};
    float lsum[2] = {0.f, 0.f};       // lane-partial; reduced in epilogue

    auto LOADK = [&](int kv0, s16x8 (&kf)[4][2]) {
#pragma unroll
      for (int mp = 0; mp < 4; ++mp)
#pragma unroll
        for (int ks = 0; ks < 2; ++ks) {
          const short* kr = Kh + (size_t)(kv0 + mp * 16 + r) * H + ks * 32 + g * 4;
          s16x4 lo = *(const s16x4*)(kr);
          s16x4 hi = *(const s16x4*)(kr + 16);
          kf[mp][ks] = __builtin_shufflevector(lo, hi, 0, 1, 2, 3, 4, 5, 6, 7);
        }
    };

    // tile-0 prefetches
    s16x8 v0 = *(const s16x8*)(Vh + (size_t)vr * H + hbase);
    s16x8 v1 = *(const s16x8*)(Vh + (size_t)vr * H + hbase + 8);
    s16x8 kfA[4][2], kfB[4][2];
    LOADK(0, kfA);

    auto TILE = [&](int tt, s16x8 (&kfc)[4][2], s16x8 (&kfn)[4][2]) {
      int kv0 = tt * 64;
      if (tt | ph) __syncthreads();   // prev compute done (incl. prev phase)
      // scatter V regs -> LDS transposed (cperm per 32-col half)
#pragma unroll
      for (int i = 0; i < 8; ++i) Vs[(hbase + i) * LDTV + vcol] = v0[i];
#pragma unroll
      for (int i = 0; i < 8; ++i) Vs[(hbase + 8 + i) * LDTV + vcol] = v1[i];
      __syncthreads();
      // prefetch V(tt+1)
      if (tt + 1 < ntiles) {
        const short* vp = Vh + (size_t)((tt + 1) * 64 + vr) * H + hbase;
        v0 = *(const s16x8*)(vp);
        v1 = *(const s16x8*)(vp + 8);
      }
      // prefetch K(tt+1) — consumed next tile, latency hides under this tile
      int tn = tt + 1;
      if (tn < ntiles && tn * 64 <= qw + 31) LOADK(tn * 64, kfn);
      if (kv0 > qw + 31) return;      // fully masked for this wave

      int mpmax = (qw + 31 - kv0) >> 4; if (mpmax > 3) mpmax = 3;
      bool need_mask = (kv0 + 63 > qw);

      float p[4][2][4];
      float rmax[2] = {-__builtin_inff(), -__builtin_inff()};
#pragma unroll
      for (int mp = 0; mp < 4; ++mp) {
        if (mp <= mpmax) {
          f32x4 st[2] = {z4, z4};
#pragma unroll
          for (int n = 0; n < 2; ++n)
#pragma unroll
            for (int ks = 0; ks < 2; ++ks)
              st[n] = MFMA16(kfc[mp][ks], qf[n][ks], st[n]);
#pragma unroll
          for (int n = 0; n < 2; ++n)
#pragma unroll
            for (int e = 0; e < 4; ++e) {
              float v = st[n][e];      // already 1/sqrt(H)-scaled via Q
              if (need_mask) {
                int kv = kv0 + mp * 16 + g * 4 + e;
                int q = qw + n * 16 + r;
                if (kv > q) v = -__builtin_inff();
              }
              p[mp][n][e] = v;
              rmax[n] = fmaxf(rmax[n], v);
            }
        } else {
#pragma unroll
          for (int n = 0; n < 2; ++n)
#pragma unroll
            for (int e = 0; e < 4; ++e) p[mp][n][e] = 0.f;
        }
      }

#pragma unroll
      for (int n = 0; n < 2; ++n) {
        rmax[n] = fmaxf(rmax[n], __shfl_xor(rmax[n], 16));
        rmax[n] = fmaxf(rmax[n], __shfl_xor(rmax[n], 32));
      }

      // defer-rescale (THR=8)
#pragma unroll
      for (int n = 0; n < 2; ++n) {
        if (!__all(rmax[n] - mrun[n] <= 8.0f)) {
          float mnew = fmaxf(mrun[n], rmax[n]);
          float sc = __expf(mrun[n] - mnew);
          lsum[n] *= sc;               // lane-partial, sc lane-consistent
          mrun[n] = mnew;
#pragma unroll
          for (int e = 0; e < 4; ++e) {
            float bs = __shfl(sc, (lane & 48) + g * 4 + e);
#pragma unroll
            for (int hb = 0; hb < 4; ++hb) o[n][hb][e] *= bs;
          }
        }
      }

#pragma unroll
      for (int mp = 0; mp < 4; ++mp) {
        if (mp <= mpmax) {
#pragma unroll
          for (int n = 0; n < 2; ++n)
#pragma unroll
            for (int e = 0; e < 4; ++e) {
              float ev = __expf(p[mp][n][e] - mrun[n]);
              p[mp][n][e] = ev;
              lsum[n] += ev;
            }
        }
      }

      // P -> bf16 A-fragments; PV
      int kvhmax = mpmax >> 1;
#pragma unroll
      for (int kvh = 0; kvh < 2; ++kvh) {
        if (kvh > kvhmax) break;
        s16x8 pa[2];
#pragma unroll
        for (int n = 0; n < 2; ++n) {
          s16x8 tmp = {f2bf(p[2 * kvh][n][0]),     f2bf(p[2 * kvh][n][1]),
                       f2bf(p[2 * kvh][n][2]),     f2bf(p[2 * kvh][n][3]),
                       f2bf(p[2 * kvh + 1][n][0]), f2bf(p[2 * kvh + 1][n][1]),
                       f2bf(p[2 * kvh + 1][n][2]), f2bf(p[2 * kvh + 1][n][3])};
          pa[n] = tmp;
        }
#pragma unroll
        for (int hb = 0; hb < 4; ++hb) {
          s16x8 vf = *(const s16x8*)(&Vs[(hb * 16 + r) * LDTV + kvh * 32 + g * 8]);
#pragma unroll
          for (int n = 0; n < 2; ++n) o[n][hb] = MFMA16(pa[n], vf, o[n][hb]);
        }
      }
    };

    for (int tt = 0; tt < ntiles; tt += 2) {  // ntiles always even
      TILE(tt, kfA, kfB);
      TILE(tt + 1, kfB, kfA);
    }

    // epilogue: reduce l, O /= l, write [B,S,N*H] bf16
#pragma unroll
    for (int n = 0; n < 2; ++n) {
      float lt = lsum[n];
      lt += __shfl_xor(lt, 16);
      lt += __shfl_xor(lt, 32);
      float il = 1.0f / lt;
#pragma unroll
      for (int e = 0; e < 4; ++e) {
        float bv = __shfl(il, (lane & 48) + g * 4 + e);
        int s = qw + n * 16 + g * 4 + e;
#pragma unroll
        for (int hb = 0; hb < 4; ++hb) {
          int c = head * 64 + hb * 16 + r;
          Ob[(size_t)(batch * 2048 + s) * 1024 + c] = f2bf(o[n][hb][e] * bv);
        }
      }
    }
  }
}

// ---------- launch ----------
extern "C" void kernel_launch(void* const* d_in, const int* in_sizes, int n_in,
                              void* d_out, int out_size, void* d_ws, size_t ws_size,
                              hipStream_t stream) {
  const float* x    = (const float*)d_in[0];   // [4,2048,1024]
  const float* Wqkv = (const float*)d_in[1];   // [1024,3072]
  const float* bqkv = (const float*)d_in[2];   // [3072]
  const float* Wout = (const float*)d_in[3];   // [1024,1024]
  const float* bout = (const float*)d_in[4];   // [1024]
  float* out = (float*)d_out;

  char* ws = (char*)d_ws;
  short* Xb    = (short*)(ws);                          // 16 MB (reused as attn-out)
  short* Wqkvb = (short*)(ws + ((size_t)16 << 20));     // 6 MB
  short* Woutb = (short*)(ws + ((size_t)22 << 20));     // 2 MB
  short* Qb    = (short*)(ws + ((size_t)24 << 20));     // 16 MB
  short* Kb    = (short*)(ws + ((size_t)40 << 20));     // 16 MB
  short* Vb    = (short*)(ws + ((size_t)56 << 20));     // 16 MB  (total 72 MB)

  cvt_f32_bf16<<<2048, 256, 0, stream>>>(x, Xb, 4 * 2048 * 1024);
  cvt_f32_bf16<<<1024, 256, 0, stream>>>(Wqkv, Wqkvb, 1024 * 3072);
  cvt_f32_bf16<<<512, 256, 0, stream>>>(Wout, Woutb, 1024 * 1024);

  gemm_qkv<<<64 * 24, 256, 0, stream>>>(Xb, Wqkvb, bqkv, Qb, Kb, Vb);
  attn<<<512, 256, 0, stream>>>(Qb, Kb, Vb, Xb);
  gemm_out<<<64 * 8, 256, 0, stream>>>(Xb, Woutb, bout, out);
}